// Round 1
// baseline (269.874 us; speedup 1.0000x reference)
//
#include <hip/hip_runtime.h>
#include <hip/hip_bf16.h>

// Problem constants
#define NN    16      // batch
#define INC   32
#define INN   65536
#define OUTC  32
#define OUTN  8192
#define MAXD  16
#define NC    512     // NN*INC

typedef __attribute__((ext_vector_type(8))) unsigned short ushort8;

// ---------------------------------------------------------------------------
// Kernel A: feat[j][r] = x[r][j] * weight[r&31][j], stored bf16 (as ushort).
// x is (512, 65536) row-major; feat is (65536, 512) row-major in d_ws.
// 64(j) x 64(r) tile. LDS tile stored [j][r] with stride 65 (2-way conflicts
// only, which are free). Global reads float4/lane, writes 16B/lane.
// UNCHANGED from the 257 µs version (bank math verified conflict-free;
// ~209 MB HBM -> ~33 µs roofline).
// ---------------------------------------------------------------------------
__global__ __launch_bounds__(256) void transpose_scale_kernel(
    const float* __restrict__ x,
    const float* __restrict__ weight,
    unsigned short* __restrict__ feat)
{
    __shared__ float tile[64][65];       // [j][r], row stride 65 floats
    const int l  = threadIdx.x;          // 0..255
    const int j0 = blockIdx.x * 64;      // 1024 blocks
    const int r0 = blockIdx.y * 64;      // 8 blocks

    #pragma unroll
    for (int it = 0; it < 4; ++it) {
        int idx = it * 256 + l;          // 0..1023
        int rl  = idx >> 4;              // 0..63
        int jj  = idx & 15;              // float4 group along j
        int r   = r0 + rl;
        int c   = r & 31;
        int j   = j0 + jj * 4;
        float4 xv = *reinterpret_cast<const float4*>(x + (size_t)r * INN + j);
        float4 wv = *reinterpret_cast<const float4*>(weight + (size_t)c * INN + j);
        tile[jj * 4 + 0][rl] = xv.x * wv.x;
        tile[jj * 4 + 1][rl] = xv.y * wv.y;
        tile[jj * 4 + 2][rl] = xv.z * wv.z;
        tile[jj * 4 + 3][rl] = xv.w * wv.w;
    }
    __syncthreads();

    #pragma unroll
    for (int p = 0; p < 2; ++p) {
        int jl = p * 32 + (l >> 3);      // 0..63
        int rs = (l & 7) * 8;            // 0..56
        ushort8 pk;
        #pragma unroll
        for (int k = 0; k < 8; ++k) {
            float v = tile[jl][rs + k];
            pk[k] = __bfloat16_as_ushort(__float2bfloat16(v));
        }
        *reinterpret_cast<ushort8*>(
            feat + (size_t)(j0 + jl) * NC + r0 + rs) = pk;
    }
}

// ---------------------------------------------------------------------------
// Kernel B: one block per OTILE=16 output nodes.
// Gather phase: unchanged (wave w handles o = 4w+i; 64 lanes x 16B = one
// full 1KB feat row per load; BW-bound on L3).
// GEMM phase v2: register-blocked 2 douts/thread (d0, d0+16) so each
// ds_read_b128 of pooled feeds 8 FMAs instead of 4 (LDS wave-instructions
// halved: 256 -> 128 per thread). Bank-quad skew qq=(q+n)&7 puts the four
// n-groups of a wave on four distinct quads (conflict-free); the skew is
// absorbed into the ctw register load so ctr[] stays statically indexed
// (no runtime-indexed register array -> no scratch).
// ---------------------------------------------------------------------------
#define OTILE 16

__global__ __launch_bounds__(256) void gather_gemm_kernel(
    const unsigned short* __restrict__ feat,
    const int*   __restrict__ A,
    const float* __restrict__ mask,
    const float* __restrict__ mw,
    const float* __restrict__ ctw,
    const float* __restrict__ ctb,
    const float* __restrict__ bias,
    float*       __restrict__ out)
{
    __shared__ float pooled[OTILE][NC];  // 32 KB
    const int l    = threadIdx.x;        // 0..255
    const int wave = l >> 6;             // 0..3
    const int lane = l & 63;
    const int o0   = blockIdx.x * OTILE; // 512 blocks

    const int n  = l >> 4;               // 0..15 : batch index for GEMM phase
    const int d0 = l & 15;               // douts d0 and d0+16

    // ---- gather phase (unchanged) ----
    #pragma unroll
    for (int i = 0; i < 4; ++i) {
        const int o  = wave * 4 + i;
        const int oo = o0 + o;
        float acc[8] = {0.f, 0.f, 0.f, 0.f, 0.f, 0.f, 0.f, 0.f};
        #pragma unroll
        for (int d = 0; d < MAXD; ++d) {
            int   j = A[oo * MAXD + d] & (INN - 1);            // wave-uniform
            float w = mw[oo * MAXD + d] * mask[oo * MAXD + d]; // wave-uniform
            ushort8 p = *reinterpret_cast<const ushort8*>(
                feat + (size_t)j * NC + lane * 8);
            #pragma unroll
            for (int k = 0; k < 8; ++k)
                acc[k] += w * __uint_as_float((unsigned)p[k] << 16);
        }
        *reinterpret_cast<float4*>(&pooled[o][lane * 8]) =
            make_float4(acc[0], acc[1], acc[2], acc[3]);
        *reinterpret_cast<float4*>(&pooled[o][lane * 8 + 4]) =
            make_float4(acc[4], acc[5], acc[6], acc[7]);
    }

    // ct_weight rows d0 / d0+16, PRE-ROTATED by n: ctr[4q+k] = ctw[d][4*((q+n)&7)+k].
    // Issued after the gather loop, before the barrier: latency hides under
    // the barrier wait for the slowest gathering wave.
    float ctr0[32], ctr1[32];
    #pragma unroll
    for (int q = 0; q < 8; ++q) {
        const int qq = (q + n) & 7;
        *reinterpret_cast<float4*>(&ctr0[4 * q]) =
            *reinterpret_cast<const float4*>(ctw + d0 * 32 + 4 * qq);
        *reinterpret_cast<float4*>(&ctr1[4 * q]) =
            *reinterpret_cast<const float4*>(ctw + (d0 + 16) * 32 + 4 * qq);
    }
    const float cb0 = ctb[d0];
    const float cb1 = ctb[d0 + 16];

    __syncthreads();

    // bias rows for this thread's two output rows (issued early, used last)
    float4 b0[4], b1[4];
    #pragma unroll
    for (int q = 0; q < 4; ++q) {
        b0[q] = *reinterpret_cast<const float4*>(
            bias + (size_t)d0 * OUTN + o0 + 4 * q);
        b1[q] = *reinterpret_cast<const float4*>(
            bias + (size_t)(d0 + 16) * OUTN + o0 + 4 * q);
    }

    // ---- GEMM phase: 16 o x 2 douts per thread ----
    float v0[OTILE], v1[OTILE];
    #pragma unroll
    for (int o = 0; o < OTILE; ++o) {
        const float* po = &pooled[o][n * 32];
        float s0 = cb0, s1 = cb1;
        #pragma unroll
        for (int q = 0; q < 8; ++q) {
            const int qq = (q + n) & 7;                 // bank-quad skew
            float4 pv = *reinterpret_cast<const float4*>(po + 4 * qq);
            s0 += pv.x * ctr0[4*q+0] + pv.y * ctr0[4*q+1]
                + pv.z * ctr0[4*q+2] + pv.w * ctr0[4*q+3];
            s1 += pv.x * ctr1[4*q+0] + pv.y * ctr1[4*q+1]
                + pv.z * ctr1[4*q+2] + pv.w * ctr1[4*q+3];
        }
        v0[o] = s0;
        v1[o] = s1;
    }

    float* r0p = out + (size_t)(n * 32 + d0)      * OUTN + o0;
    float* r1p = out + (size_t)(n * 32 + d0 + 16) * OUTN + o0;
    #pragma unroll
    for (int q = 0; q < 4; ++q) {
        *reinterpret_cast<float4*>(r0p + 4 * q) = make_float4(
            v0[4*q+0] + b0[q].x, v0[4*q+1] + b0[q].y,
            v0[4*q+2] + b0[q].z, v0[4*q+3] + b0[q].w);
        *reinterpret_cast<float4*>(r1p + 4 * q) = make_float4(
            v1[4*q+0] + b1[q].x, v1[4*q+1] + b1[q].y,
            v1[4*q+2] + b1[q].z, v1[4*q+3] + b1[q].w);
    }
}

extern "C" void kernel_launch(void* const* d_in, const int* in_sizes, int n_in,
                              void* d_out, int out_size, void* d_ws, size_t ws_size,
                              hipStream_t stream)
{
    const float* x      = (const float*)d_in[0];   // (16,32,65536)
    const int*   A      = (const int*)  d_in[1];   // (8192,16) int32 on device
    const float* weight = (const float*)d_in[2];   // (32,65536)
    const float* mask   = (const float*)d_in[3];   // (8192,16,1)
    const float* mw     = (const float*)d_in[4];   // (8192,16,1)
    const float* ctw    = (const float*)d_in[5];   // (32,32)
    const float* ctb    = (const float*)d_in[6];   // (32,)
    const float* bias   = (const float*)d_in[7];   // (32,8192)
    float* out = (float*)d_out;                    // (16,32,8192)

    unsigned short* feat = (unsigned short*)d_ws;  // (65536, 512) bf16 = 67 MB

    dim3 gA(INN / 64, NC / 64);                    // 1024 x 8
    transpose_scale_kernel<<<gA, 256, 0, stream>>>(x, weight, feat);

    gather_gemm_kernel<<<OUTN / OTILE, 256, 0, stream>>>(
        feat, A, mask, mw, ctw, ctb, bias, out);
}

// Round 2
// 261.485 us; speedup vs baseline: 1.0321x; 1.0321x over previous
//
#include <hip/hip_runtime.h>
#include <hip/hip_bf16.h>

// Problem constants
#define NN    16      // batch
#define INC   32
#define INN   65536
#define OUTC  32
#define OUTN  8192
#define MAXD  16
#define NC    512     // NN*INC

typedef __attribute__((ext_vector_type(8))) unsigned short ushort8;

// ---------------------------------------------------------------------------
// Kernel A: feat[j][r] = x[r][j] * weight[r&31][j], stored bf16 (as ushort).
// x is (512, 65536) row-major; feat is (65536, 512) row-major in d_ws.
// 64(j) x 64(r) tile. LDS tile stored [j][r] with stride 65 (2-way conflicts
// only, which are free). Global reads float4/lane, writes 16B/lane.
// UNCHANGED (~209 MB HBM -> ~33 µs roofline; bank math verified clean).
// ---------------------------------------------------------------------------
__global__ __launch_bounds__(256) void transpose_scale_kernel(
    const float* __restrict__ x,
    const float* __restrict__ weight,
    unsigned short* __restrict__ feat)
{
    __shared__ float tile[64][65];       // [j][r], row stride 65 floats
    const int l  = threadIdx.x;          // 0..255
    const int j0 = blockIdx.x * 64;      // 1024 blocks
    const int r0 = blockIdx.y * 64;      // 8 blocks

    #pragma unroll
    for (int it = 0; it < 4; ++it) {
        int idx = it * 256 + l;          // 0..1023
        int rl  = idx >> 4;              // 0..63
        int jj  = idx & 15;              // float4 group along j
        int r   = r0 + rl;
        int c   = r & 31;
        int j   = j0 + jj * 4;
        float4 xv = *reinterpret_cast<const float4*>(x + (size_t)r * INN + j);
        float4 wv = *reinterpret_cast<const float4*>(weight + (size_t)c * INN + j);
        tile[jj * 4 + 0][rl] = xv.x * wv.x;
        tile[jj * 4 + 1][rl] = xv.y * wv.y;
        tile[jj * 4 + 2][rl] = xv.z * wv.z;
        tile[jj * 4 + 3][rl] = xv.w * wv.w;
    }
    __syncthreads();

    #pragma unroll
    for (int p = 0; p < 2; ++p) {
        int jl = p * 32 + (l >> 3);      // 0..63
        int rs = (l & 7) * 8;            // 0..56
        ushort8 pk;
        #pragma unroll
        for (int k = 0; k < 8; ++k) {
            float v = tile[jl][rs + k];
            pk[k] = __bfloat16_as_ushort(__float2bfloat16(v));
        }
        *reinterpret_cast<ushort8*>(
            feat + (size_t)(j0 + jl) * NC + r0 + rs) = pk;
    }
}

// ---------------------------------------------------------------------------
// Kernel B v3: OTILE=8 -> 1024 blocks (was 512). Round-0 measured 2 blocks/CU
// (grid-limited, 2 waves/SIMD) on a latency-bound L3 gather; halving the
// tile doubles resident blocks/CU to 4 (16 waves/CU) with LDS 16 KB and
// VGPR ~<128 both leaving headroom. GEMM phase reverted to the round-0
// form: broadcast b128 reads of pooled (same-address across 32 lanes =
// free; the 2 distinct n-addresses are 2-way quad aliasing = free), one
// dout per thread, ctr[32] only -> low VGPR pressure.
// ---------------------------------------------------------------------------
#define OTILE 8

__global__ __launch_bounds__(256) void gather_gemm_kernel(
    const unsigned short* __restrict__ feat,
    const int*   __restrict__ A,
    const float* __restrict__ mask,
    const float* __restrict__ mw,
    const float* __restrict__ ctw,
    const float* __restrict__ ctb,
    const float* __restrict__ bias,
    float*       __restrict__ out)
{
    __shared__ float pooled[OTILE][NC];  // 16 KB
    const int l    = threadIdx.x;        // 0..255
    const int wave = l >> 6;             // 0..3
    const int lane = l & 63;
    const int o0   = blockIdx.x * OTILE; // 1024 blocks

    // ct_weight row for this thread's dout, into registers (8 x float4).
    const int dout = l & 31;
    float ctr[32];
    #pragma unroll
    for (int q = 0; q < 8; ++q)
        *reinterpret_cast<float4*>(&ctr[4 * q]) =
            *reinterpret_cast<const float4*>(ctw + dout * 32 + 4 * q);
    const float cb = ctb[dout];

    // Gather phase: each wave owns 2 output nodes; 16 independent 1KB row
    // loads per node in flight.
    #pragma unroll
    for (int i = 0; i < 2; ++i) {
        const int o  = wave * 2 + i;
        const int oo = o0 + o;
        float acc[8] = {0.f, 0.f, 0.f, 0.f, 0.f, 0.f, 0.f, 0.f};
        #pragma unroll
        for (int d = 0; d < MAXD; ++d) {
            int   j = A[oo * MAXD + d] & (INN - 1);            // wave-uniform
            float w = mw[oo * MAXD + d] * mask[oo * MAXD + d]; // wave-uniform
            ushort8 p = *reinterpret_cast<const ushort8*>(
                feat + (size_t)j * NC + lane * 8);
            #pragma unroll
            for (int k = 0; k < 8; ++k)
                acc[k] += w * __uint_as_float((unsigned)p[k] << 16);
        }
        *reinterpret_cast<float4*>(&pooled[o][lane * 8]) =
            make_float4(acc[0], acc[1], acc[2], acc[3]);
        *reinterpret_cast<float4*>(&pooled[o][lane * 8 + 4]) =
            make_float4(acc[4], acc[5], acc[6], acc[7]);
    }
    __syncthreads();

    // GEMM phase: 512 (n,dout) pairs, 2 n's per thread, 8 o's each.
    #pragma unroll
    for (int h = 0; h < 2; ++h) {
        const int n = (l >> 5) + 8 * h;  // 0..15
        float vals[OTILE];
        #pragma unroll
        for (int o = 0; o < OTILE; ++o) {
            float s = cb;
            #pragma unroll
            for (int q = 0; q < 8; ++q) {
                float4 pv = *reinterpret_cast<const float4*>(
                    &pooled[o][n * 32 + 4 * q]);        // broadcast read
                s += pv.x * ctr[4 * q + 0] + pv.y * ctr[4 * q + 1]
                   + pv.z * ctr[4 * q + 2] + pv.w * ctr[4 * q + 3];
            }
            vals[o] = s + bias[(size_t)dout * OUTN + o0 + o];
        }
        float4* outp = reinterpret_cast<float4*>(
            out + ((size_t)(n * 32 + dout)) * OUTN + o0);
        #pragma unroll
        for (int q = 0; q < 2; ++q)
            outp[q] = make_float4(vals[4*q], vals[4*q+1], vals[4*q+2], vals[4*q+3]);
    }
}

extern "C" void kernel_launch(void* const* d_in, const int* in_sizes, int n_in,
                              void* d_out, int out_size, void* d_ws, size_t ws_size,
                              hipStream_t stream)
{
    const float* x      = (const float*)d_in[0];   // (16,32,65536)
    const int*   A      = (const int*)  d_in[1];   // (8192,16) int32 on device
    const float* weight = (const float*)d_in[2];   // (32,65536)
    const float* mask   = (const float*)d_in[3];   // (8192,16,1)
    const float* mw     = (const float*)d_in[4];   // (8192,16,1)
    const float* ctw    = (const float*)d_in[5];   // (32,32)
    const float* ctb    = (const float*)d_in[6];   // (32,)
    const float* bias   = (const float*)d_in[7];   // (32,8192)
    float* out = (float*)d_out;                    // (16,32,8192)

    unsigned short* feat = (unsigned short*)d_ws;  // (65536, 512) bf16 = 67 MB

    dim3 gA(INN / 64, NC / 64);                    // 1024 x 8
    transpose_scale_kernel<<<gA, 256, 0, stream>>>(x, weight, feat);

    gather_gemm_kernel<<<OUTN / OTILE, 256, 0, stream>>>(
        feat, A, mask, mw, ctw, ctb, bias, out);
}